// Round 10
// baseline (280.440 us; speedup 1.0000x reference)
//
#include <hip/hip_runtime.h>
#include <stdint.h>

typedef __attribute__((ext_vector_type(8))) short short8;
typedef __attribute__((ext_vector_type(4))) float f32x4;
typedef __attribute__((ext_vector_type(4))) int i32x4;

constexpr float EPSV  = 1e-6f;
constexpr float LNEPS = 1e-5f;

// ---- workspace / LDS byte layout ----
constexpr int W1OFF = 0;          // 32768 B : W1^T bf16 [256 h][64 kslot], XOR-swizzled
constexpr int W2OFF = 32768;      // 65536 B : W2^T bf16 [128 h2][256 kslot], XOR-swizzled
constexpr int W3OFF = 98304;      //  4096 B : W3^T bf16 [16 r][128 kslot], XOR-swizzled
constexpr int WIMG  = 102400;     // total weight image
constexpr int XBOFF = 102400;     // LDS: Xb (8 chunks, padded stride)
constexpr int XCH   = 2080;       // Xb chunk stride bytes (128 n * 16B + 32 pad)
constexpr int LDSA  = WIMG + 8 * XCH;   // 119040 B
// NOTE (r1-r8 forensics): the r0 mlp body below is the ONLY variant the
// compiler allocates spill-free at 512 threads (VGPR 128, FETCH 34 MB,
// WRITE 23 MB). Every deviation — pair-tiles (r2), reg-LN (r4/r5), fused
// stream (r6), W2-from-global (r8) — made the scheduler hoist loads / extend
// live ranges past the 128-reg cap and spill 200-900 MB to scratch. DO NOT
// edit the mlp loop body; verify FETCH/WRITE_SIZE fingerprint every round.

constexpr int ZCH   = 1312;       // sigma kernel: Ztb group stride (80 dims*16B + 32 pad)
constexpr int NG    = 8;          // 8 row-groups (64 rows/chunk)
constexpr int GTOFF = NG * ZCH;   // 10496
constexpr int SBUF  = GTOFF + 1024;     // one staging buffer: z groups + gamma = 11520 B
constexpr int LDSB  = 2 * SBUF;         // double-buffered -> 23040 B (2 blocks/CU OK)

__device__ __forceinline__ ushort f2bf(float f) {
  union { float f; uint32_t u; } v; v.f = f;
  uint32_t r = v.u + 0x7fffu + ((v.u >> 16) & 1u);   // round-nearest-even
  return (ushort)(r >> 16);
}
__device__ __forceinline__ float bf2f(ushort h) {
  union { uint32_t u; float f; } v; v.u = ((uint32_t)h) << 16;
  return v.f;
}

// ---------------- prep: bake bf16 weight images + zero gsum (fused) ----------------
__global__ void prep_kernel(const float* __restrict__ W1, const float* __restrict__ W2,
                            const float* __restrict__ W3, uint8_t* __restrict__ wsb) {
  const int idx = blockIdx.x * 256 + threadIdx.x;   // 0..51199
  if (blockIdx.x == 0 && threadIdx.x < 8)
    ((float*)(wsb + WIMG))[threadIdx.x] = 0.f;      // gsum zero (disjoint region)
  ushort val; uint32_t a;
  if (idx < 16384) {                                // W1^T: slot p = 32s+8g+j -> k = p
    const int h = idx >> 6, p = idx & 63;
    a = ((uint32_t)(h * 128 + p * 2)) ^ ((uint32_t)(h & 7) << 4);
    val = f2bf(W1[p * 256 + h]);
  } else if (idx < 49152) {                         // W2^T
    const int i2 = idx - 16384;
    const int h2 = i2 >> 8, p = i2 & 255;
    const int s = p >> 5, g = (p >> 3) & 3, j = p & 7;
    const int k = 32 * s + 16 * (j >> 2) + 4 * g + (j & 3);
    a = (uint32_t)W2OFF + (((uint32_t)(h2 * 512 + p * 2)) ^ ((uint32_t)(h2 & 7) << 4));
    val = f2bf(W2[k * 128 + h2]);
  } else {                                          // W3^T padded to 16 rows
    const int i3 = idx - 49152;
    const int r = i3 >> 7, p = i3 & 127;
    const int s = p >> 5, g = (p >> 3) & 3, j = p & 7;
    const int k = 32 * s + 16 * (j >> 2) + 4 * g + (j & 3);
    a = (uint32_t)W3OFF + (((uint32_t)(r * 256 + p * 2)) ^ ((uint32_t)(r & 7) << 4));
    val = (r < 8) ? f2bf(W3[k * 8 + r]) : (ushort)0;
  }
  *(ushort*)(wsb + a) = val;
}

// ---------------- kernel A: persistent LN + 3-layer MLP (MFMA) + softmax ----
// Round-0 body, verbatim (verified spill-free: VGPR 128, FETCH 34 MB, 156 us).
__global__ __launch_bounds__(512, 1)
void mlp_kernel(const float* __restrict__ z,
                const float* __restrict__ lng, const float* __restrict__ lnb,
                const float* __restrict__ b1, const float* __restrict__ b2,
                const float* __restrict__ b3,
                const uint8_t* __restrict__ wimg,
                float* __restrict__ gamma_out, float* __restrict__ gsum,
                int N, int ntiles)
{
  __shared__ uint8_t lds[LDSA];
  const int tid = threadIdx.x;

  // stage weight image once (pre-swizzled; linear copy)
  {
    const i32x4* src = (const i32x4*)wimg;
    i32x4* dst = (i32x4*)lds;
    for (int i = tid; i < WIMG / 16; i += 512) dst[i] = src[i];
  }
  __syncthreads();

  const int lane = tid & 63;
  const int w = tid >> 6;            // wave id (owns its 16-row tiles)
  const int m = lane & 15;
  const int g = lane >> 4;           // also LN quarter
  const uint32_t swz = (uint32_t)((m & 7) << 4);

  f32x4 gacc = {0.f, 0.f, 0.f, 0.f};
  const int nwaves = gridDim.x * 8;

  for (int t = blockIdx.x * 8 + w; t < ntiles; t += nwaves) {
    const int64_t n0 = (int64_t)t * 16;

    // ---- in-wave LayerNorm: lane (r=m, q=g) handles row n0+m, dims 16g..16g+15 ----
    {
      int64_t row = n0 + m;
      if (row >= N) row = N - 1;
      const f32x4* zr = (const f32x4*)(z + row * 64 + g * 16);
      f32x4 zv[4];
      float s = 0.f, s2 = 0.f;
#pragma unroll
      for (int k = 0; k < 4; ++k) {
        zv[k] = zr[k];
#pragma unroll
        for (int e = 0; e < 4; ++e) { s += zv[k][e]; s2 = fmaf(zv[k][e], zv[k][e], s2); }
      }
      s  += __shfl_xor(s, 16);  s  += __shfl_xor(s, 32);
      s2 += __shfl_xor(s2, 16); s2 += __shfl_xor(s2, 32);
      const float mean = s * (1.f / 64.f);
      const float rstd = rsqrtf(s2 * (1.f / 64.f) - mean * mean + LNEPS);
#pragma unroll
      for (int h = 0; h < 2; ++h) {
        union { short8 v; ushort u[8]; } pk;
#pragma unroll
        for (int i = 0; i < 8; ++i) {
          const int li = h * 8 + i;            // 0..15 within quarter
          const int d = g * 16 + li;
          const float x = fmaf((zv[li >> 2][li & 3] - mean) * rstd, lng[d], lnb[d]);
          pk.u[i] = f2bf(x);
        }
        *(short8*)(&lds[XBOFF + (2 * g + h) * XCH + (16 * w + m) * 16]) = pk.v;
      }
    }
    // no barrier: wave reads back only its own rows

    // ---- GEMM1: H1^T = W1^T @ X^T (16 h-tiles, k=64 -> 2 steps) ----
    f32x4 acc1[16];
#pragma unroll
    for (int ht = 0; ht < 16; ++ht)
      acc1[ht] = *(const f32x4*)(b1 + ht * 16 + g * 4);
#pragma unroll
    for (int s = 0; s < 2; ++s) {
      const short8 bfrag = *(const short8*)(&lds[XBOFF + (4 * s + g) * XCH + (16 * w + m) * 16]);
      const uint32_t koff = ((uint32_t)(64 * s + 16 * g)) ^ swz;
#pragma unroll
      for (int ht = 0; ht < 16; ++ht) {
        const short8 afrag = *(const short8*)(&lds[(uint32_t)((m + 16 * ht) * 128) + koff]);
        acc1[ht] = __builtin_amdgcn_mfma_f32_16x16x32_bf16(afrag, bfrag, acc1[ht], 0, 0, 0);
      }
    }

    // relu + pack -> B-frags for GEMM2
    short8 h1f[8];
#pragma unroll
    for (int s = 0; s < 8; ++s) {
      union { short8 v; ushort u[8]; } pk;
#pragma unroll
      for (int e = 0; e < 4; ++e) pk.u[e]     = f2bf(fmaxf(acc1[2 * s][e],     0.f));
#pragma unroll
      for (int e = 0; e < 4; ++e) pk.u[4 + e] = f2bf(fmaxf(acc1[2 * s + 1][e], 0.f));
      h1f[s] = pk.v;
    }

    // ---- GEMM2: H2^T = W2^T @ H1^T (8 h2-tiles, k=256 -> 8 steps) ----
    f32x4 acc2[8];
#pragma unroll
    for (int at = 0; at < 8; ++at)
      acc2[at] = *(const f32x4*)(b2 + at * 16 + g * 4);
#pragma unroll
    for (int s = 0; s < 8; ++s) {
      const uint32_t koff = ((uint32_t)(64 * s + 16 * g)) ^ swz;
#pragma unroll
      for (int at = 0; at < 8; ++at) {
        const short8 afrag = *(const short8*)(&lds[(uint32_t)W2OFF + (uint32_t)((m + 16 * at) * 512) + koff]);
        acc2[at] = __builtin_amdgcn_mfma_f32_16x16x32_bf16(afrag, h1f[s], acc2[at], 0, 0, 0);
      }
    }

    short8 h2f[4];
#pragma unroll
    for (int s = 0; s < 4; ++s) {
      union { short8 v; ushort u[8]; } pk;
#pragma unroll
      for (int e = 0; e < 4; ++e) pk.u[e]     = f2bf(fmaxf(acc2[2 * s][e],     0.f));
#pragma unroll
      for (int e = 0; e < 4; ++e) pk.u[4 + e] = f2bf(fmaxf(acc2[2 * s + 1][e], 0.f));
      h2f[s] = pk.v;
    }

    // ---- GEMM3: logits^T = W3^T @ H2^T (1 tile, k=128 -> 4 steps) ----
    f32x4 acc3;
    if (g < 2) acc3 = *(const f32x4*)(b3 + 4 * g);
    else       acc3 = (f32x4){0.f, 0.f, 0.f, 0.f};
#pragma unroll
    for (int s = 0; s < 4; ++s) {
      const uint32_t koff = ((uint32_t)(64 * s + 16 * g)) ^ swz;
      const short8 afrag = *(const short8*)(&lds[(uint32_t)W3OFF + (uint32_t)(m * 256) + koff]);
      acc3 = __builtin_amdgcn_mfma_f32_16x16x32_bf16(afrag, h2f[s], acc3, 0, 0, 0);
    }

    // ---- softmax over K=8 (rows split across lane-groups 0,1; col = batch row) ----
    float mx = fmaxf(fmaxf(acc3[0], acc3[1]), fmaxf(acc3[2], acc3[3]));
    mx = fmaxf(mx, __shfl_xor(mx, 16));
    const float e0 = __expf(acc3[0] - mx), e1 = __expf(acc3[1] - mx);
    const float e2 = __expf(acc3[2] - mx), e3 = __expf(acc3[3] - mx);
    float se = e0 + e1 + e2 + e3;
    se += __shfl_xor(se, 16);
    const float inv = 1.f / se;

    const int64_t rowg = n0 + m;
    const bool valid = (g < 2) && (rowg < N);
    const f32x4 gv = { e0 * inv, e1 * inv, e2 * inv, e3 * inv };
    if (valid) {
      *(f32x4*)(gamma_out + rowg * 8 + 4 * g) = gv;
      gacc[0] += gv[0]; gacc[1] += gv[1]; gacc[2] += gv[2]; gacc[3] += gv[3];
    }
  }

  // one atomic batch per wave
#pragma unroll
  for (int i = 0; i < 4; ++i) {
    float v = gacc[i];
    v += __shfl_xor(v, 1); v += __shfl_xor(v, 2);
    v += __shfl_xor(v, 4); v += __shfl_xor(v, 8);
    if (m == 0 && g < 2) atomicAdd(&gsum[4 * g + i], v);
  }
}

// ---------------- kernel B: M_c = Zhat^T (gamma_c .* Z) via MFMA (Zhat dim64 = 1) ----
// 1024 threads = 16 waves. Wave (c = w&7, p = w>>3) owns output columns
// 32p..32p+31 of component c -> acc[5][2], no cross-wave reduce.
// r9: gamma on the B side (2 frags instead of 5). r10: (a) double-buffered
// LDS staging -> ONE barrier per 64-row chunk (was 2); (b) grid 512 blocks
// (2 blocks/CU, 32 waves) so one block computes while the other barriers.
__global__ __launch_bounds__(1024)
void sigma_kernel(const float* __restrict__ z, const float* __restrict__ gamma,
                  float* __restrict__ Mpart, int N, int rpb)
{
  __shared__ uint8_t lds[LDSB];
  const int tid = threadIdx.x;
  const int lane = tid & 63;
  const int w = tid >> 6;           // 0..15
  const int c = w & 7;              // component
  const int p = w >> 3;             // column half
  const int m = lane & 15;
  const int g = lane >> 4;

  // constant pad dims 64..79 in BOTH buffers (dim 64 = 1.0 -> S row; 65..79 = 0)
  {
    const int gg = tid >> 7, dd = 64 + ((tid >> 3) & 15), jj = tid & 7;
    const ushort pv = (dd == 64) ? (ushort)0x3F80 : (ushort)0;
    *(ushort*)(&lds[gg * ZCH + dd * 16 + jj * 2]) = pv;
    *(ushort*)(&lds[SBUF + gg * ZCH + dd * 16 + jj * 2]) = pv;
  }

  f32x4 acc[5][2];
#pragma unroll
  for (int it = 0; it < 5; ++it)
#pragma unroll
    for (int jt = 0; jt < 2; ++jt) acc[it][jt] = (f32x4){0.f, 0.f, 0.f, 0.f};

  const int64_t row0 = (int64_t)blockIdx.x * rpb;
  const int n16 = tid >> 4, d0 = (tid & 15) * 4;   // staging: row-in-chunk, dim base
  const int gc = n16 >> 3, jn = n16 & 7;

  f32x4 zpre; float gpre = 0.f;
  {   // prologue: load chunk 0 and stage it into buffer 0
    int64_t rowz = row0 + n16; if (rowz >= N) rowz = N - 1;
    zpre = *(const f32x4*)(z + rowz * 64 + d0);
    if (tid < 512) {
      const int64_t rg = row0 + (tid >> 3);
      gpre = (rg < N) ? gamma[rg * 8 + (tid & 7)] : 0.f;
    }
#pragma unroll
    for (int i = 0; i < 4; ++i)
      *(ushort*)(&lds[gc * ZCH + (d0 + i) * 16 + jn * 2]) = f2bf(zpre[i]);
    if (tid < 512)
      *(ushort*)(&lds[GTOFF + (tid & 7) * 128 + (tid >> 3) * 2]) = f2bf(gpre);
  }
  __syncthreads();   // buffer 0 ready

  int cur = 0;
  for (int rr = 0; rr < rpb; rr += 64, cur ^= 1) {
    // issue next chunk's global loads (latency hides under this chunk's MFMA)
    const bool more = (rr + 64 < rpb);
    if (more) {
      int64_t rowz = row0 + rr + 64 + n16; if (rowz >= N) rowz = N - 1;
      zpre = *(const f32x4*)(z + rowz * 64 + d0);
      if (tid < 512) {
        const int64_t rg = row0 + rr + 64 + (tid >> 3);
        gpre = (rg < N) ? gamma[rg * 8 + (tid & 7)] : 0.f;
      }
    }

    // compute from buf[cur]
    const uint8_t* buf = &lds[cur * SBUF];
#pragma unroll
    for (int kg = 0; kg < 2; ++kg) {
      union { short8 v; ushort u[8]; } gu;
      gu.v = *(const short8*)(&buf[GTOFF + c * 128 + kg * 64 + g * 16]);
      float gf[8];
#pragma unroll
      for (int j = 0; j < 8; ++j) gf[j] = bf2f(gu.u[j]);

      const uint8_t* zg = &buf[(4 * kg + g) * ZCH];
      // gamma-weight the 2 B-frags (columns 32p..32p+31)
      union { short8 v; ushort u[8]; } zb0, zb1, wf0, wf1;
      zb0.v = *(const short8*)(&zg[(m + 16 * (2 * p + 0)) * 16]);
      zb1.v = *(const short8*)(&zg[(m + 16 * (2 * p + 1)) * 16]);
#pragma unroll
      for (int j = 0; j < 8; ++j) {
        wf0.u[j] = f2bf(gf[j] * bf2f(zb0.u[j]));
        wf1.u[j] = f2bf(gf[j] * bf2f(zb1.u[j]));
      }
      // A side: raw Zhat fragments (incl. pad rows), straight ds_reads
#pragma unroll
      for (int it = 0; it < 5; ++it) {
        const short8 za = *(const short8*)(&zg[(m + 16 * it) * 16]);
        acc[it][0] = __builtin_amdgcn_mfma_f32_16x16x32_bf16(za, wf0.v, acc[it][0], 0, 0, 0);
        acc[it][1] = __builtin_amdgcn_mfma_f32_16x16x32_bf16(za, wf1.v, acc[it][1], 0, 0, 0);
      }
    }

    // stage next chunk into the other buffer (its readers passed last barrier)
    if (more) {
      uint8_t* nb = &lds[(cur ^ 1) * SBUF];
#pragma unroll
      for (int i = 0; i < 4; ++i)
        *(ushort*)(&nb[gc * ZCH + (d0 + i) * 16 + jn * 2]) = f2bf(zpre[i]);
      if (tid < 512)
        *(ushort*)(&nb[GTOFF + (tid & 7) * 128 + (tid >> 3) * 2]) = f2bf(gpre);
    }
    __syncthreads();   // one barrier per chunk
  }

  // write partials: rows 0..63 = M, row 64 = S; wave writes its own column half
  float* mp = Mpart + ((size_t)blockIdx.x * 8 + c) * (65 * 64);
#pragma unroll
  for (int it = 0; it < 5; ++it)
#pragma unroll
    for (int jt = 0; jt < 2; ++jt)
#pragma unroll
      for (int r = 0; r < 4; ++r) {
        const int rowi = it * 16 + g * 4 + r;
        if (rowi <= 64) mp[rowi * 64 + (2 * p + jt) * 16 + m] = acc[it][jt][r];
      }
}

// ---------------- reduce S (row 64 of partials) -> Sfin, mu, phi ----------------
__global__ void reduce_s_kernel(const float* __restrict__ Mpart,
                                const float* __restrict__ gsum,
                                float* __restrict__ Sfin,
                                float* __restrict__ phi_out, float* __restrict__ mu_out,
                                int nb, int N)
{
  __shared__ float sh[4][64];
  const int c = blockIdx.x;
  const int tid = threadIdx.x;
  const int q = tid >> 6, d = tid & 63;
  const int per = (nb + 3) >> 2;
  const int b0 = q * per, b1 = min(nb, b0 + per);
  float s = 0.f;
  for (int b = b0; b < b1; ++b)
    s += Mpart[((size_t)b * 8 + c) * 4160 + 4096 + d];
  sh[q][d] = s;
  __syncthreads();
  if (tid < 64) {
    const float t = sh[0][d] + sh[1][d] + sh[2][d] + sh[3][d];
    Sfin[c * 64 + d] = t;
    mu_out[c * 64 + d] = t / (gsum[c] + EPSV);
  }
  if (c == 0 && tid == 0) {
    float p[8], tot = 0.f;
    for (int j = 0; j < 8; ++j) { p[j] = gsum[j] / (float)N + EPSV / 8.f; tot += p[j]; }
    for (int j = 0; j < 8; ++j) phi_out[j] = p[j] / tot;
  }
}

// ---------------- reduce M (coalesced, one element per thread) -> sigma ----------
__global__ void reduce_m_kernel(const float* __restrict__ Mpart,
                                const float* __restrict__ Sfin,
                                const float* __restrict__ gsum,
                                float* __restrict__ sig_out, int nb)
{
  const int e = blockIdx.x * 128 + threadIdx.x;   // 0..32767 = (c, i, j); 256 blocks
  const int c = e >> 12;
  const int ij = e & 4095;
  const int i = ij >> 6, j = ij & 63;
  float s0 = 0.f, s1 = 0.f, s2 = 0.f, s3 = 0.f;
  int b = 0;
  for (; b + 3 < nb; b += 4) {
    s0 += Mpart[((size_t)(b + 0) * 8 + c) * 4160 + ij];
    s1 += Mpart[((size_t)(b + 1) * 8 + c) * 4160 + ij];
    s2 += Mpart[((size_t)(b + 2) * 8 + c) * 4160 + ij];
    s3 += Mpart[((size_t)(b + 3) * 8 + c) * 4160 + ij];
  }
  for (; b < nb; ++b)
    s0 += Mpart[((size_t)b * 8 + c) * 4160 + ij];
  const float msum = (s0 + s1) + (s2 + s3);
  const float gs = gsum[c];
  const float g1 = gs + EPSV;
  const float coef = (gs - 2.f * g1) / (g1 * g1 * g1);
  float v = msum / g1 + Sfin[c * 64 + i] * Sfin[c * 64 + j] * coef;
  if (i == j) v += EPSV;
  sig_out[e] = v;
}

extern "C" void kernel_launch(void* const* d_in, const int* in_sizes, int n_in,
                              void* d_out, int out_size, void* d_ws, size_t ws_size,
                              hipStream_t stream)
{
  const float* z   = (const float*)d_in[0];
  const float* lng = (const float*)d_in[1];
  const float* lnb = (const float*)d_in[2];
  const float* W1  = (const float*)d_in[3];
  const float* b1  = (const float*)d_in[4];
  const float* W2  = (const float*)d_in[5];
  const float* b2  = (const float*)d_in[6];
  const float* W3  = (const float*)d_in[7];
  const float* b3  = (const float*)d_in[8];
  const int N = in_sizes[0] / 64;

  float* out       = (float*)d_out;
  float* gamma_out = out;
  float* phi_out   = out + (size_t)N * 8;
  float* mu_out    = phi_out + 8;
  float* sig_out   = mu_out + 512;

  uint8_t* wsb = (uint8_t*)d_ws;
  float* gsum  = (float*)(wsb + WIMG);
  float* Sfin  = (float*)(wsb + WIMG + 32);
  float* Mpart = (float*)(wsb + WIMG + 32 + 2048);

  int nbB = 512;   // 2 blocks/CU for sigma (capped by workspace below)
  {
    const size_t need1 = (size_t)WIMG + 32 + 2048;
    const size_t avail = (ws_size > need1) ? ws_size - need1 : 0;
    size_t fit = avail / (4160ull * 8ull * 4ull);
    if (fit < 1) fit = 1;
    if ((size_t)nbB > fit) nbB = (int)fit;
  }
  int rpb = (N + nbB - 1) / nbB;
  rpb = (rpb + 63) & ~63;

  const int ntiles = (N + 15) / 16;

  prep_kernel<<<200, 256, 0, stream>>>(W1, W2, W3, wsb);
  mlp_kernel<<<256, 512, 0, stream>>>(z, lng, lnb, b1, b2, b3, wsb,
                                      gamma_out, gsum, N, ntiles);
  sigma_kernel<<<nbB, 1024, 0, stream>>>(z, gamma_out, Mpart, N, rpb);
  reduce_s_kernel<<<8, 256, 0, stream>>>(Mpart, gsum, Sfin, phi_out, mu_out, nbB, N);
  reduce_m_kernel<<<256, 128, 0, stream>>>(Mpart, Sfin, gsum, sig_out, nbB);
}

// Round 11
// 235.514 us; speedup vs baseline: 1.1908x; 1.1908x over previous
//
#include <hip/hip_runtime.h>
#include <stdint.h>

typedef __attribute__((ext_vector_type(8))) short short8;
typedef __attribute__((ext_vector_type(4))) float f32x4;
typedef __attribute__((ext_vector_type(4))) int i32x4;

constexpr float EPSV  = 1e-6f;
constexpr float LNEPS = 1e-5f;

// ---- workspace / LDS byte layout ----
constexpr int W1OFF = 0;          // 32768 B : W1^T bf16 [256 h][64 kslot], XOR-swizzled
constexpr int W2OFF = 32768;      // 65536 B : W2^T bf16 [128 h2][256 kslot], XOR-swizzled
constexpr int W3OFF = 98304;      //  4096 B : W3^T bf16 [16 r][128 kslot], XOR-swizzled
constexpr int WIMG  = 102400;     // total weight image
constexpr int XBOFF = 102400;     // LDS: Xb (8 chunks, padded stride)
constexpr int XCH   = 2080;       // Xb chunk stride bytes (128 n * 16B + 32 pad)
constexpr int LDSA  = WIMG + 8 * XCH;   // 119040 B
// NOTE (r1-r8 forensics): the r0 mlp body below is the ONLY variant the
// compiler allocates spill-free at 512 threads (VGPR 128, FETCH 34 MB,
// WRITE 23 MB). Every deviation — pair-tiles (r2), reg-LN (r4/r5), fused
// stream (r6), W2-from-global (r8) — made the scheduler hoist loads / extend
// live ranges past the 128-reg cap and spill 200-900 MB to scratch. DO NOT
// edit the mlp loop body; verify FETCH/WRITE_SIZE fingerprint every round.
// NOTE (r10): sigma nbB=512 + post-MFMA dbuf staging regressed 44 us (2nd
// block never co-resident at sigma's VGPR count; Mpart doubling taxed
// reduces; staging moved onto critical path). r9 sigma structure is the
// verified optimum: single buffer, 2 barriers/chunk, nbB=256.

constexpr int ZCH   = 1312;       // sigma kernel: Ztb group stride (80 dims*16B + 32 pad)
constexpr int NG    = 8;          // 8 row-groups (64 rows/chunk)
constexpr int GTOFF = NG * ZCH;   // 10496
constexpr int LDSB  = GTOFF + 1024;     // + gamma [8c][64n] bf16

__device__ __forceinline__ ushort f2bf(float f) {
  union { float f; uint32_t u; } v; v.f = f;
  uint32_t r = v.u + 0x7fffu + ((v.u >> 16) & 1u);   // round-nearest-even
  return (ushort)(r >> 16);
}
__device__ __forceinline__ float bf2f(ushort h) {
  union { uint32_t u; float f; } v; v.u = ((uint32_t)h) << 16;
  return v.f;
}

// ---------------- prep: bake bf16 weight images + zero gsum (fused) ----------------
__global__ void prep_kernel(const float* __restrict__ W1, const float* __restrict__ W2,
                            const float* __restrict__ W3, uint8_t* __restrict__ wsb) {
  const int idx = blockIdx.x * 256 + threadIdx.x;   // 0..51199
  if (blockIdx.x == 0 && threadIdx.x < 8)
    ((float*)(wsb + WIMG))[threadIdx.x] = 0.f;      // gsum zero (disjoint region)
  ushort val; uint32_t a;
  if (idx < 16384) {                                // W1^T: slot p = 32s+8g+j -> k = p
    const int h = idx >> 6, p = idx & 63;
    a = ((uint32_t)(h * 128 + p * 2)) ^ ((uint32_t)(h & 7) << 4);
    val = f2bf(W1[p * 256 + h]);
  } else if (idx < 49152) {                         // W2^T
    const int i2 = idx - 16384;
    const int h2 = i2 >> 8, p = i2 & 255;
    const int s = p >> 5, g = (p >> 3) & 3, j = p & 7;
    const int k = 32 * s + 16 * (j >> 2) + 4 * g + (j & 3);
    a = (uint32_t)W2OFF + (((uint32_t)(h2 * 512 + p * 2)) ^ ((uint32_t)(h2 & 7) << 4));
    val = f2bf(W2[k * 128 + h2]);
  } else {                                          // W3^T padded to 16 rows
    const int i3 = idx - 49152;
    const int r = i3 >> 7, p = i3 & 127;
    const int s = p >> 5, g = (p >> 3) & 3, j = p & 7;
    const int k = 32 * s + 16 * (j >> 2) + 4 * g + (j & 3);
    a = (uint32_t)W3OFF + (((uint32_t)(r * 256 + p * 2)) ^ ((uint32_t)(r & 7) << 4));
    val = (r < 8) ? f2bf(W3[k * 8 + r]) : (ushort)0;
  }
  *(ushort*)(wsb + a) = val;
}

// ---------------- kernel A: persistent LN + 3-layer MLP (MFMA) + softmax ----
// Round-0 body, verbatim (verified spill-free: VGPR 128, FETCH 34 MB, 156 us).
__global__ __launch_bounds__(512, 1)
void mlp_kernel(const float* __restrict__ z,
                const float* __restrict__ lng, const float* __restrict__ lnb,
                const float* __restrict__ b1, const float* __restrict__ b2,
                const float* __restrict__ b3,
                const uint8_t* __restrict__ wimg,
                float* __restrict__ gamma_out, float* __restrict__ gsum,
                int N, int ntiles)
{
  __shared__ uint8_t lds[LDSA];
  const int tid = threadIdx.x;

  // stage weight image once (pre-swizzled; linear copy)
  {
    const i32x4* src = (const i32x4*)wimg;
    i32x4* dst = (i32x4*)lds;
    for (int i = tid; i < WIMG / 16; i += 512) dst[i] = src[i];
  }
  __syncthreads();

  const int lane = tid & 63;
  const int w = tid >> 6;            // wave id (owns its 16-row tiles)
  const int m = lane & 15;
  const int g = lane >> 4;           // also LN quarter
  const uint32_t swz = (uint32_t)((m & 7) << 4);

  f32x4 gacc = {0.f, 0.f, 0.f, 0.f};
  const int nwaves = gridDim.x * 8;

  for (int t = blockIdx.x * 8 + w; t < ntiles; t += nwaves) {
    const int64_t n0 = (int64_t)t * 16;

    // ---- in-wave LayerNorm: lane (r=m, q=g) handles row n0+m, dims 16g..16g+15 ----
    {
      int64_t row = n0 + m;
      if (row >= N) row = N - 1;
      const f32x4* zr = (const f32x4*)(z + row * 64 + g * 16);
      f32x4 zv[4];
      float s = 0.f, s2 = 0.f;
#pragma unroll
      for (int k = 0; k < 4; ++k) {
        zv[k] = zr[k];
#pragma unroll
        for (int e = 0; e < 4; ++e) { s += zv[k][e]; s2 = fmaf(zv[k][e], zv[k][e], s2); }
      }
      s  += __shfl_xor(s, 16);  s  += __shfl_xor(s, 32);
      s2 += __shfl_xor(s2, 16); s2 += __shfl_xor(s2, 32);
      const float mean = s * (1.f / 64.f);
      const float rstd = rsqrtf(s2 * (1.f / 64.f) - mean * mean + LNEPS);
#pragma unroll
      for (int h = 0; h < 2; ++h) {
        union { short8 v; ushort u[8]; } pk;
#pragma unroll
        for (int i = 0; i < 8; ++i) {
          const int li = h * 8 + i;            // 0..15 within quarter
          const int d = g * 16 + li;
          const float x = fmaf((zv[li >> 2][li & 3] - mean) * rstd, lng[d], lnb[d]);
          pk.u[i] = f2bf(x);
        }
        *(short8*)(&lds[XBOFF + (2 * g + h) * XCH + (16 * w + m) * 16]) = pk.v;
      }
    }
    // no barrier: wave reads back only its own rows

    // ---- GEMM1: H1^T = W1^T @ X^T (16 h-tiles, k=64 -> 2 steps) ----
    f32x4 acc1[16];
#pragma unroll
    for (int ht = 0; ht < 16; ++ht)
      acc1[ht] = *(const f32x4*)(b1 + ht * 16 + g * 4);
#pragma unroll
    for (int s = 0; s < 2; ++s) {
      const short8 bfrag = *(const short8*)(&lds[XBOFF + (4 * s + g) * XCH + (16 * w + m) * 16]);
      const uint32_t koff = ((uint32_t)(64 * s + 16 * g)) ^ swz;
#pragma unroll
      for (int ht = 0; ht < 16; ++ht) {
        const short8 afrag = *(const short8*)(&lds[(uint32_t)((m + 16 * ht) * 128) + koff]);
        acc1[ht] = __builtin_amdgcn_mfma_f32_16x16x32_bf16(afrag, bfrag, acc1[ht], 0, 0, 0);
      }
    }

    // relu + pack -> B-frags for GEMM2
    short8 h1f[8];
#pragma unroll
    for (int s = 0; s < 8; ++s) {
      union { short8 v; ushort u[8]; } pk;
#pragma unroll
      for (int e = 0; e < 4; ++e) pk.u[e]     = f2bf(fmaxf(acc1[2 * s][e],     0.f));
#pragma unroll
      for (int e = 0; e < 4; ++e) pk.u[4 + e] = f2bf(fmaxf(acc1[2 * s + 1][e], 0.f));
      h1f[s] = pk.v;
    }

    // ---- GEMM2: H2^T = W2^T @ H1^T (8 h2-tiles, k=256 -> 8 steps) ----
    f32x4 acc2[8];
#pragma unroll
    for (int at = 0; at < 8; ++at)
      acc2[at] = *(const f32x4*)(b2 + at * 16 + g * 4);
#pragma unroll
    for (int s = 0; s < 8; ++s) {
      const uint32_t koff = ((uint32_t)(64 * s + 16 * g)) ^ swz;
#pragma unroll
      for (int at = 0; at < 8; ++at) {
        const short8 afrag = *(const short8*)(&lds[(uint32_t)W2OFF + (uint32_t)((m + 16 * at) * 512) + koff]);
        acc2[at] = __builtin_amdgcn_mfma_f32_16x16x32_bf16(afrag, h1f[s], acc2[at], 0, 0, 0);
      }
    }

    short8 h2f[4];
#pragma unroll
    for (int s = 0; s < 4; ++s) {
      union { short8 v; ushort u[8]; } pk;
#pragma unroll
      for (int e = 0; e < 4; ++e) pk.u[e]     = f2bf(fmaxf(acc2[2 * s][e],     0.f));
#pragma unroll
      for (int e = 0; e < 4; ++e) pk.u[4 + e] = f2bf(fmaxf(acc2[2 * s + 1][e], 0.f));
      h2f[s] = pk.v;
    }

    // ---- GEMM3: logits^T = W3^T @ H2^T (1 tile, k=128 -> 4 steps) ----
    f32x4 acc3;
    if (g < 2) acc3 = *(const f32x4*)(b3 + 4 * g);
    else       acc3 = (f32x4){0.f, 0.f, 0.f, 0.f};
#pragma unroll
    for (int s = 0; s < 4; ++s) {
      const uint32_t koff = ((uint32_t)(64 * s + 16 * g)) ^ swz;
      const short8 afrag = *(const short8*)(&lds[(uint32_t)W3OFF + (uint32_t)(m * 256) + koff]);
      acc3 = __builtin_amdgcn_mfma_f32_16x16x32_bf16(afrag, h2f[s], acc3, 0, 0, 0);
    }

    // ---- softmax over K=8 (rows split across lane-groups 0,1; col = batch row) ----
    float mx = fmaxf(fmaxf(acc3[0], acc3[1]), fmaxf(acc3[2], acc3[3]));
    mx = fmaxf(mx, __shfl_xor(mx, 16));
    const float e0 = __expf(acc3[0] - mx), e1 = __expf(acc3[1] - mx);
    const float e2 = __expf(acc3[2] - mx), e3 = __expf(acc3[3] - mx);
    float se = e0 + e1 + e2 + e3;
    se += __shfl_xor(se, 16);
    const float inv = 1.f / se;

    const int64_t rowg = n0 + m;
    const bool valid = (g < 2) && (rowg < N);
    const f32x4 gv = { e0 * inv, e1 * inv, e2 * inv, e3 * inv };
    if (valid) {
      *(f32x4*)(gamma_out + rowg * 8 + 4 * g) = gv;
      gacc[0] += gv[0]; gacc[1] += gv[1]; gacc[2] += gv[2]; gacc[3] += gv[3];
    }
  }

  // one atomic batch per wave
#pragma unroll
  for (int i = 0; i < 4; ++i) {
    float v = gacc[i];
    v += __shfl_xor(v, 1); v += __shfl_xor(v, 2);
    v += __shfl_xor(v, 4); v += __shfl_xor(v, 8);
    if (m == 0 && g < 2) atomicAdd(&gsum[4 * g + i], v);
  }
}

// ---------------- kernel B: M_c = Zhat^T (gamma_c .* Z) via MFMA (Zhat dim64 = 1) ----
// r9 structure, verbatim (verified): 1024 threads = 16 waves, wave (c, p) owns
// columns 32p..32p+31 of component c; gamma on the B side (2 frags); 64-row
// chunks, 2 barriers/chunk, register prefetch of next chunk before MFMA phase.
__global__ __launch_bounds__(1024)
void sigma_kernel(const float* __restrict__ z, const float* __restrict__ gamma,
                  float* __restrict__ Mpart, int N, int rpb)
{
  __shared__ uint8_t lds[LDSB];
  const int tid = threadIdx.x;
  const int lane = tid & 63;
  const int w = tid >> 6;           // 0..15
  const int c = w & 7;              // component
  const int p = w >> 3;             // column half
  const int m = lane & 15;
  const int g = lane >> 4;

  // constant pad dims 64..79 for all 8 groups (dim 64 = 1.0 -> S row; 65..79 = 0)
  {
    const int gg = tid >> 7, dd = 64 + ((tid >> 3) & 15), jj = tid & 7;
    *(ushort*)(&lds[gg * ZCH + dd * 16 + jj * 2]) = (dd == 64) ? (ushort)0x3F80 : (ushort)0;
  }

  f32x4 acc[5][2];
#pragma unroll
  for (int it = 0; it < 5; ++it)
#pragma unroll
    for (int jt = 0; jt < 2; ++jt) acc[it][jt] = (f32x4){0.f, 0.f, 0.f, 0.f};

  const int64_t row0 = (int64_t)blockIdx.x * rpb;
  const int n16 = tid >> 4, d0 = (tid & 15) * 4;   // staging: row-in-chunk, dim base
  const int gc = n16 >> 3, jn = n16 & 7;

  f32x4 zpre; float gpre = 0.f;
  {   // prologue prefetch chunk 0
    int64_t rowz = row0 + n16; if (rowz >= N) rowz = N - 1;
    zpre = *(const f32x4*)(z + rowz * 64 + d0);
    if (tid < 512) {
      const int64_t rg = row0 + (tid >> 3);
      gpre = (rg < N) ? gamma[rg * 8 + (tid & 7)] : 0.f;
    }
  }

  for (int rr = 0; rr < rpb; rr += 64) {
    __syncthreads();
    {   // write staged chunk -> LDS (transposed-blocked [group][dim][8n] bf16)
#pragma unroll
      for (int i = 0; i < 4; ++i)
        *(ushort*)(&lds[gc * ZCH + (d0 + i) * 16 + jn * 2]) = f2bf(zpre[i]);
      if (tid < 512)
        *(ushort*)(&lds[GTOFF + (tid & 7) * 128 + (tid >> 3) * 2]) = f2bf(gpre);
    }
    __syncthreads();

    // issue next chunk's loads (latency hides under the MFMA phase below)
    if (rr + 64 < rpb) {
      int64_t rowz = row0 + rr + 64 + n16; if (rowz >= N) rowz = N - 1;
      zpre = *(const f32x4*)(z + rowz * 64 + d0);
      if (tid < 512) {
        const int64_t rg = row0 + rr + 64 + (tid >> 3);
        gpre = (rg < N) ? gamma[rg * 8 + (tid & 7)] : 0.f;
      }
    }

#pragma unroll
    for (int kg = 0; kg < 2; ++kg) {
      union { short8 v; ushort u[8]; } gu;
      gu.v = *(const short8*)(&lds[GTOFF + c * 128 + kg * 64 + g * 16]);
      float gf[8];
#pragma unroll
      for (int j = 0; j < 8; ++j) gf[j] = bf2f(gu.u[j]);

      const uint8_t* zg = &lds[(4 * kg + g) * ZCH];
      // gamma-weight the 2 B-frags (columns 32p..32p+31)
      union { short8 v; ushort u[8]; } zb0, zb1, wf0, wf1;
      zb0.v = *(const short8*)(&zg[(m + 16 * (2 * p + 0)) * 16]);
      zb1.v = *(const short8*)(&zg[(m + 16 * (2 * p + 1)) * 16]);
#pragma unroll
      for (int j = 0; j < 8; ++j) {
        wf0.u[j] = f2bf(gf[j] * bf2f(zb0.u[j]));
        wf1.u[j] = f2bf(gf[j] * bf2f(zb1.u[j]));
      }
      // A side: raw Zhat fragments (incl. pad rows), straight ds_reads
#pragma unroll
      for (int it = 0; it < 5; ++it) {
        const short8 za = *(const short8*)(&zg[(m + 16 * it) * 16]);
        acc[it][0] = __builtin_amdgcn_mfma_f32_16x16x32_bf16(za, wf0.v, acc[it][0], 0, 0, 0);
        acc[it][1] = __builtin_amdgcn_mfma_f32_16x16x32_bf16(za, wf1.v, acc[it][1], 0, 0, 0);
      }
    }
  }

  // write partials: rows 0..63 = M, row 64 = S; wave writes its own column half
  float* mp = Mpart + ((size_t)blockIdx.x * 8 + c) * (65 * 64);
#pragma unroll
  for (int it = 0; it < 5; ++it)
#pragma unroll
    for (int jt = 0; jt < 2; ++jt)
#pragma unroll
      for (int r = 0; r < 4; ++r) {
        const int rowi = it * 16 + g * 4 + r;
        if (rowi <= 64) mp[rowi * 64 + (2 * p + jt) * 16 + m] = acc[it][jt][r];
      }
}

// ---------------- reduce S (row 64 of partials) -> Sfin, mu, phi ----------------
__global__ void reduce_s_kernel(const float* __restrict__ Mpart,
                                const float* __restrict__ gsum,
                                float* __restrict__ Sfin,
                                float* __restrict__ phi_out, float* __restrict__ mu_out,
                                int nb, int N)
{
  __shared__ float sh[4][64];
  const int c = blockIdx.x;
  const int tid = threadIdx.x;
  const int q = tid >> 6, d = tid & 63;
  const int per = (nb + 3) >> 2;
  const int b0 = q * per, b1 = min(nb, b0 + per);
  float s = 0.f;
  for (int b = b0; b < b1; ++b)
    s += Mpart[((size_t)b * 8 + c) * 4160 + 4096 + d];
  sh[q][d] = s;
  __syncthreads();
  if (tid < 64) {
    const float t = sh[0][d] + sh[1][d] + sh[2][d] + sh[3][d];
    Sfin[c * 64 + d] = t;
    mu_out[c * 64 + d] = t / (gsum[c] + EPSV);
  }
  if (c == 0 && tid == 0) {
    float p[8], tot = 0.f;
    for (int j = 0; j < 8; ++j) { p[j] = gsum[j] / (float)N + EPSV / 8.f; tot += p[j]; }
    for (int j = 0; j < 8; ++j) phi_out[j] = p[j] / tot;
  }
}

// ---------------- reduce M (coalesced, one element per thread) -> sigma ----------
__global__ void reduce_m_kernel(const float* __restrict__ Mpart,
                                const float* __restrict__ Sfin,
                                const float* __restrict__ gsum,
                                float* __restrict__ sig_out, int nb)
{
  const int e = blockIdx.x * 128 + threadIdx.x;   // 0..32767 = (c, i, j); 256 blocks
  const int c = e >> 12;
  const int ij = e & 4095;
  const int i = ij >> 6, j = ij & 63;
  float s0 = 0.f, s1 = 0.f, s2 = 0.f, s3 = 0.f;
  int b = 0;
  for (; b + 3 < nb; b += 4) {
    s0 += Mpart[((size_t)(b + 0) * 8 + c) * 4160 + ij];
    s1 += Mpart[((size_t)(b + 1) * 8 + c) * 4160 + ij];
    s2 += Mpart[((size_t)(b + 2) * 8 + c) * 4160 + ij];
    s3 += Mpart[((size_t)(b + 3) * 8 + c) * 4160 + ij];
  }
  for (; b < nb; ++b)
    s0 += Mpart[((size_t)b * 8 + c) * 4160 + ij];
  const float msum = (s0 + s1) + (s2 + s3);
  const float gs = gsum[c];
  const float g1 = gs + EPSV;
  const float coef = (gs - 2.f * g1) / (g1 * g1 * g1);
  float v = msum / g1 + Sfin[c * 64 + i] * Sfin[c * 64 + j] * coef;
  if (i == j) v += EPSV;
  sig_out[e] = v;
}

extern "C" void kernel_launch(void* const* d_in, const int* in_sizes, int n_in,
                              void* d_out, int out_size, void* d_ws, size_t ws_size,
                              hipStream_t stream)
{
  const float* z   = (const float*)d_in[0];
  const float* lng = (const float*)d_in[1];
  const float* lnb = (const float*)d_in[2];
  const float* W1  = (const float*)d_in[3];
  const float* b1  = (const float*)d_in[4];
  const float* W2  = (const float*)d_in[5];
  const float* b2  = (const float*)d_in[6];
  const float* W3  = (const float*)d_in[7];
  const float* b3  = (const float*)d_in[8];
  const int N = in_sizes[0] / 64;

  float* out       = (float*)d_out;
  float* gamma_out = out;
  float* phi_out   = out + (size_t)N * 8;
  float* mu_out    = phi_out + 8;
  float* sig_out   = mu_out + 512;

  uint8_t* wsb = (uint8_t*)d_ws;
  float* gsum  = (float*)(wsb + WIMG);
  float* Sfin  = (float*)(wsb + WIMG + 32);
  float* Mpart = (float*)(wsb + WIMG + 32 + 2048);

  int nbB = 256;
  {
    const size_t need1 = (size_t)WIMG + 32 + 2048;
    const size_t avail = (ws_size > need1) ? ws_size - need1 : 0;
    size_t fit = avail / (4160ull * 8ull * 4ull);
    if (fit < 1) fit = 1;
    if ((size_t)nbB > fit) nbB = (int)fit;
  }
  int rpb = (N + nbB - 1) / nbB;
  rpb = (rpb + 63) & ~63;

  const int ntiles = (N + 15) / 16;

  prep_kernel<<<200, 256, 0, stream>>>(W1, W2, W3, wsb);
  mlp_kernel<<<256, 512, 0, stream>>>(z, lng, lnb, b1, b2, b3, wsb,
                                      gamma_out, gsum, N, ntiles);
  sigma_kernel<<<nbB, 1024, 0, stream>>>(z, gamma_out, Mpart, N, rpb);
  reduce_s_kernel<<<8, 256, 0, stream>>>(Mpart, gsum, Sfin, phi_out, mu_out, nbB, N);
  reduce_m_kernel<<<256, 128, 0, stream>>>(Mpart, Sfin, gsum, sig_out, nbB);
}

// Round 12
// 234.992 us; speedup vs baseline: 1.1934x; 1.0022x over previous
//
#include <hip/hip_runtime.h>
#include <stdint.h>

typedef __attribute__((ext_vector_type(8))) short short8;
typedef __attribute__((ext_vector_type(4))) float f32x4;
typedef __attribute__((ext_vector_type(4))) int i32x4;

constexpr float EPSV  = 1e-6f;
constexpr float LNEPS = 1e-5f;

// ---- workspace / LDS byte layout ----
constexpr int W1OFF = 0;          // 32768 B : W1^T bf16 [256 h][64 kslot], XOR-swizzled
constexpr int W2OFF = 32768;      // 65536 B : W2^T bf16 [128 h2][256 kslot], XOR-swizzled
constexpr int W3OFF = 98304;      //  4096 B : W3^T bf16 [16 r][128 kslot], XOR-swizzled
constexpr int WIMG  = 102400;     // total weight image
constexpr int XBOFF = 102400;     // LDS: Xb (8 chunks, padded stride)
constexpr int XCH   = 2080;       // Xb chunk stride bytes (128 n * 16B + 32 pad)
constexpr int LDSA  = WIMG + 8 * XCH;   // 119040 B
// NOTE (r1-r8 forensics): the r0 mlp body below is the ONLY variant the
// compiler allocates spill-free at 512 threads (VGPR 128, FETCH 34 MB,
// WRITE 23 MB). Every deviation — pair-tiles (r2), reg-LN (r4/r5), fused
// stream (r6), W2-from-global (r8) — made the scheduler hoist loads / extend
// live ranges past the 128-reg cap and spill 200-900 MB to scratch. DO NOT
// edit the mlp loop body; verify FETCH/WRITE_SIZE fingerprint every round.
// NOTE (r10): sigma nbB=512 + post-MFMA dbuf staging regressed 44 us. That
// test was confounded (grid + staging order changed together). r12 tests the
// barrier-frequency hypothesis cleanly: 128-row chunks, same order, nbB=256.

constexpr int ZCH   = 1312;       // sigma kernel: Ztb group stride (80 dims*16B + 32 pad)
constexpr int NG    = 16;         // 16 row-groups (128 rows/chunk)
constexpr int GTOFF = NG * ZCH;   // 20992
constexpr int LDSB  = GTOFF + 2048;     // + gamma [8c][128n] bf16 = 23040 B

__device__ __forceinline__ ushort f2bf(float f) {
  union { float f; uint32_t u; } v; v.f = f;
  uint32_t r = v.u + 0x7fffu + ((v.u >> 16) & 1u);   // round-nearest-even
  return (ushort)(r >> 16);
}
__device__ __forceinline__ float bf2f(ushort h) {
  union { uint32_t u; float f; } v; v.u = ((uint32_t)h) << 16;
  return v.f;
}

// ---------------- prep: bake bf16 weight images + zero gsum (fused) ----------------
__global__ void prep_kernel(const float* __restrict__ W1, const float* __restrict__ W2,
                            const float* __restrict__ W3, uint8_t* __restrict__ wsb) {
  const int idx = blockIdx.x * 256 + threadIdx.x;   // 0..51199
  if (blockIdx.x == 0 && threadIdx.x < 8)
    ((float*)(wsb + WIMG))[threadIdx.x] = 0.f;      // gsum zero (disjoint region)
  ushort val; uint32_t a;
  if (idx < 16384) {                                // W1^T: slot p = 32s+8g+j -> k = p
    const int h = idx >> 6, p = idx & 63;
    a = ((uint32_t)(h * 128 + p * 2)) ^ ((uint32_t)(h & 7) << 4);
    val = f2bf(W1[p * 256 + h]);
  } else if (idx < 49152) {                         // W2^T
    const int i2 = idx - 16384;
    const int h2 = i2 >> 8, p = i2 & 255;
    const int s = p >> 5, g = (p >> 3) & 3, j = p & 7;
    const int k = 32 * s + 16 * (j >> 2) + 4 * g + (j & 3);
    a = (uint32_t)W2OFF + (((uint32_t)(h2 * 512 + p * 2)) ^ ((uint32_t)(h2 & 7) << 4));
    val = f2bf(W2[k * 128 + h2]);
  } else {                                          // W3^T padded to 16 rows
    const int i3 = idx - 49152;
    const int r = i3 >> 7, p = i3 & 127;
    const int s = p >> 5, g = (p >> 3) & 3, j = p & 7;
    const int k = 32 * s + 16 * (j >> 2) + 4 * g + (j & 3);
    a = (uint32_t)W3OFF + (((uint32_t)(r * 256 + p * 2)) ^ ((uint32_t)(r & 7) << 4));
    val = (r < 8) ? f2bf(W3[k * 8 + r]) : (ushort)0;
  }
  *(ushort*)(wsb + a) = val;
}

// ---------------- kernel A: persistent LN + 3-layer MLP (MFMA) + softmax ----
// Round-0 body, verbatim (verified spill-free: VGPR 128, FETCH 34 MB, 156 us).
__global__ __launch_bounds__(512, 1)
void mlp_kernel(const float* __restrict__ z,
                const float* __restrict__ lng, const float* __restrict__ lnb,
                const float* __restrict__ b1, const float* __restrict__ b2,
                const float* __restrict__ b3,
                const uint8_t* __restrict__ wimg,
                float* __restrict__ gamma_out, float* __restrict__ gsum,
                int N, int ntiles)
{
  __shared__ uint8_t lds[LDSA];
  const int tid = threadIdx.x;

  // stage weight image once (pre-swizzled; linear copy)
  {
    const i32x4* src = (const i32x4*)wimg;
    i32x4* dst = (i32x4*)lds;
    for (int i = tid; i < WIMG / 16; i += 512) dst[i] = src[i];
  }
  __syncthreads();

  const int lane = tid & 63;
  const int w = tid >> 6;            // wave id (owns its 16-row tiles)
  const int m = lane & 15;
  const int g = lane >> 4;           // also LN quarter
  const uint32_t swz = (uint32_t)((m & 7) << 4);

  f32x4 gacc = {0.f, 0.f, 0.f, 0.f};
  const int nwaves = gridDim.x * 8;

  for (int t = blockIdx.x * 8 + w; t < ntiles; t += nwaves) {
    const int64_t n0 = (int64_t)t * 16;

    // ---- in-wave LayerNorm: lane (r=m, q=g) handles row n0+m, dims 16g..16g+15 ----
    {
      int64_t row = n0 + m;
      if (row >= N) row = N - 1;
      const f32x4* zr = (const f32x4*)(z + row * 64 + g * 16);
      f32x4 zv[4];
      float s = 0.f, s2 = 0.f;
#pragma unroll
      for (int k = 0; k < 4; ++k) {
        zv[k] = zr[k];
#pragma unroll
        for (int e = 0; e < 4; ++e) { s += zv[k][e]; s2 = fmaf(zv[k][e], zv[k][e], s2); }
      }
      s  += __shfl_xor(s, 16);  s  += __shfl_xor(s, 32);
      s2 += __shfl_xor(s2, 16); s2 += __shfl_xor(s2, 32);
      const float mean = s * (1.f / 64.f);
      const float rstd = rsqrtf(s2 * (1.f / 64.f) - mean * mean + LNEPS);
#pragma unroll
      for (int h = 0; h < 2; ++h) {
        union { short8 v; ushort u[8]; } pk;
#pragma unroll
        for (int i = 0; i < 8; ++i) {
          const int li = h * 8 + i;            // 0..15 within quarter
          const int d = g * 16 + li;
          const float x = fmaf((zv[li >> 2][li & 3] - mean) * rstd, lng[d], lnb[d]);
          pk.u[i] = f2bf(x);
        }
        *(short8*)(&lds[XBOFF + (2 * g + h) * XCH + (16 * w + m) * 16]) = pk.v;
      }
    }
    // no barrier: wave reads back only its own rows

    // ---- GEMM1: H1^T = W1^T @ X^T (16 h-tiles, k=64 -> 2 steps) ----
    f32x4 acc1[16];
#pragma unroll
    for (int ht = 0; ht < 16; ++ht)
      acc1[ht] = *(const f32x4*)(b1 + ht * 16 + g * 4);
#pragma unroll
    for (int s = 0; s < 2; ++s) {
      const short8 bfrag = *(const short8*)(&lds[XBOFF + (4 * s + g) * XCH + (16 * w + m) * 16]);
      const uint32_t koff = ((uint32_t)(64 * s + 16 * g)) ^ swz;
#pragma unroll
      for (int ht = 0; ht < 16; ++ht) {
        const short8 afrag = *(const short8*)(&lds[(uint32_t)((m + 16 * ht) * 128) + koff]);
        acc1[ht] = __builtin_amdgcn_mfma_f32_16x16x32_bf16(afrag, bfrag, acc1[ht], 0, 0, 0);
      }
    }

    // relu + pack -> B-frags for GEMM2
    short8 h1f[8];
#pragma unroll
    for (int s = 0; s < 8; ++s) {
      union { short8 v; ushort u[8]; } pk;
#pragma unroll
      for (int e = 0; e < 4; ++e) pk.u[e]     = f2bf(fmaxf(acc1[2 * s][e],     0.f));
#pragma unroll
      for (int e = 0; e < 4; ++e) pk.u[4 + e] = f2bf(fmaxf(acc1[2 * s + 1][e], 0.f));
      h1f[s] = pk.v;
    }

    // ---- GEMM2: H2^T = W2^T @ H1^T (8 h2-tiles, k=256 -> 8 steps) ----
    f32x4 acc2[8];
#pragma unroll
    for (int at = 0; at < 8; ++at)
      acc2[at] = *(const f32x4*)(b2 + at * 16 + g * 4);
#pragma unroll
    for (int s = 0; s < 8; ++s) {
      const uint32_t koff = ((uint32_t)(64 * s + 16 * g)) ^ swz;
#pragma unroll
      for (int at = 0; at < 8; ++at) {
        const short8 afrag = *(const short8*)(&lds[(uint32_t)W2OFF + (uint32_t)((m + 16 * at) * 512) + koff]);
        acc2[at] = __builtin_amdgcn_mfma_f32_16x16x32_bf16(afrag, h1f[s], acc2[at], 0, 0, 0);
      }
    }

    short8 h2f[4];
#pragma unroll
    for (int s = 0; s < 4; ++s) {
      union { short8 v; ushort u[8]; } pk;
#pragma unroll
      for (int e = 0; e < 4; ++e) pk.u[e]     = f2bf(fmaxf(acc2[2 * s][e],     0.f));
#pragma unroll
      for (int e = 0; e < 4; ++e) pk.u[4 + e] = f2bf(fmaxf(acc2[2 * s + 1][e], 0.f));
      h2f[s] = pk.v;
    }

    // ---- GEMM3: logits^T = W3^T @ H2^T (1 tile, k=128 -> 4 steps) ----
    f32x4 acc3;
    if (g < 2) acc3 = *(const f32x4*)(b3 + 4 * g);
    else       acc3 = (f32x4){0.f, 0.f, 0.f, 0.f};
#pragma unroll
    for (int s = 0; s < 4; ++s) {
      const uint32_t koff = ((uint32_t)(64 * s + 16 * g)) ^ swz;
      const short8 afrag = *(const short8*)(&lds[(uint32_t)W3OFF + (uint32_t)(m * 256) + koff]);
      acc3 = __builtin_amdgcn_mfma_f32_16x16x32_bf16(afrag, h2f[s], acc3, 0, 0, 0);
    }

    // ---- softmax over K=8 (rows split across lane-groups 0,1; col = batch row) ----
    float mx = fmaxf(fmaxf(acc3[0], acc3[1]), fmaxf(acc3[2], acc3[3]));
    mx = fmaxf(mx, __shfl_xor(mx, 16));
    const float e0 = __expf(acc3[0] - mx), e1 = __expf(acc3[1] - mx);
    const float e2 = __expf(acc3[2] - mx), e3 = __expf(acc3[3] - mx);
    float se = e0 + e1 + e2 + e3;
    se += __shfl_xor(se, 16);
    const float inv = 1.f / se;

    const int64_t rowg = n0 + m;
    const bool valid = (g < 2) && (rowg < N);
    const f32x4 gv = { e0 * inv, e1 * inv, e2 * inv, e3 * inv };
    if (valid) {
      *(f32x4*)(gamma_out + rowg * 8 + 4 * g) = gv;
      gacc[0] += gv[0]; gacc[1] += gv[1]; gacc[2] += gv[2]; gacc[3] += gv[3];
    }
  }

  // one atomic batch per wave
#pragma unroll
  for (int i = 0; i < 4; ++i) {
    float v = gacc[i];
    v += __shfl_xor(v, 1); v += __shfl_xor(v, 2);
    v += __shfl_xor(v, 4); v += __shfl_xor(v, 8);
    if (m == 0 && g < 2) atomicAdd(&gsum[4 * g + i], v);
  }
}

// ---------------- kernel B: M_c = Zhat^T (gamma_c .* Z) via MFMA (Zhat dim64 = 1) ----
// r9 structure with 128-row chunks (r12): same staging order, same 2-barrier
// pattern, nbB=256 — only the chunk size doubles (barriers per block 26->14,
// MFMA per barrier interval 20->40 per wave). Wave (c, p) owns columns
// 32p..32p+31 of component c; gamma on the B side (2 frags per kg).
__global__ __launch_bounds__(1024)
void sigma_kernel(const float* __restrict__ z, const float* __restrict__ gamma,
                  float* __restrict__ Mpart, int N, int rpb)
{
  __shared__ uint8_t lds[LDSB];
  const int tid = threadIdx.x;
  const int lane = tid & 63;
  const int w = tid >> 6;           // 0..15
  const int c = w & 7;              // component
  const int p = w >> 3;             // column half
  const int m = lane & 15;
  const int g = lane >> 4;

  // constant pad dims 64..79 for all 16 groups (dim 64 = 1.0 -> S row; 65..79 = 0)
  {
    const int dd = 64 + ((tid >> 3) & 15), jj = tid & 7;
    const ushort pv = (dd == 64) ? (ushort)0x3F80 : (ushort)0;
    *(ushort*)(&lds[(tid >> 7) * ZCH + dd * 16 + jj * 2]) = pv;
    *(ushort*)(&lds[((tid >> 7) + 8) * ZCH + dd * 16 + jj * 2]) = pv;
  }

  f32x4 acc[5][2];
#pragma unroll
  for (int it = 0; it < 5; ++it)
#pragma unroll
    for (int jt = 0; jt < 2; ++jt) acc[it][jt] = (f32x4){0.f, 0.f, 0.f, 0.f};

  const int64_t row0 = (int64_t)blockIdx.x * rpb;
  const int n16 = tid >> 4, d0 = (tid & 15) * 4;   // staging: row-in-half-chunk, dim base
  const int gc = n16 >> 3, jn = n16 & 7;

  f32x4 zpre0, zpre1; float gpre = 0.f;
  {   // prologue prefetch chunk 0 (rows n16 and n16+64)
    int64_t r0z = row0 + n16;      if (r0z >= N) r0z = N - 1;
    int64_t r1z = row0 + 64 + n16; if (r1z >= N) r1z = N - 1;
    zpre0 = *(const f32x4*)(z + r0z * 64 + d0);
    zpre1 = *(const f32x4*)(z + r1z * 64 + d0);
    const int64_t rg = row0 + (tid >> 3);
    gpre = (rg < N) ? gamma[rg * 8 + (tid & 7)] : 0.f;
  }

  for (int rr = 0; rr < rpb; rr += 128) {
    __syncthreads();
    {   // write staged chunk -> LDS (transposed-blocked [group][dim][8n] bf16)
#pragma unroll
      for (int i = 0; i < 4; ++i) {
        *(ushort*)(&lds[gc * ZCH + (d0 + i) * 16 + jn * 2])       = f2bf(zpre0[i]);
        *(ushort*)(&lds[(gc + 8) * ZCH + (d0 + i) * 16 + jn * 2]) = f2bf(zpre1[i]);
      }
      *(ushort*)(&lds[GTOFF + (tid & 7) * 256 + (tid >> 3) * 2]) = f2bf(gpre);
    }
    __syncthreads();

    // issue next chunk's loads (latency hides under the MFMA phase below)
    if (rr + 128 < rpb) {
      int64_t r0z = row0 + rr + 128 + n16;      if (r0z >= N) r0z = N - 1;
      int64_t r1z = row0 + rr + 128 + 64 + n16; if (r1z >= N) r1z = N - 1;
      zpre0 = *(const f32x4*)(z + r0z * 64 + d0);
      zpre1 = *(const f32x4*)(z + r1z * 64 + d0);
      const int64_t rg = row0 + rr + 128 + (tid >> 3);
      gpre = (rg < N) ? gamma[rg * 8 + (tid & 7)] : 0.f;
    }

#pragma unroll
    for (int kg = 0; kg < 4; ++kg) {
      union { short8 v; ushort u[8]; } gu;
      gu.v = *(const short8*)(&lds[GTOFF + c * 256 + kg * 64 + g * 16]);
      float gf[8];
#pragma unroll
      for (int j = 0; j < 8; ++j) gf[j] = bf2f(gu.u[j]);

      const uint8_t* zg = &lds[(4 * kg + g) * ZCH];
      // gamma-weight the 2 B-frags (columns 32p..32p+31)
      union { short8 v; ushort u[8]; } zb0, zb1, wf0, wf1;
      zb0.v = *(const short8*)(&zg[(m + 16 * (2 * p + 0)) * 16]);
      zb1.v = *(const short8*)(&zg[(m + 16 * (2 * p + 1)) * 16]);
#pragma unroll
      for (int j = 0; j < 8; ++j) {
        wf0.u[j] = f2bf(gf[j] * bf2f(zb0.u[j]));
        wf1.u[j] = f2bf(gf[j] * bf2f(zb1.u[j]));
      }
      // A side: raw Zhat fragments (incl. pad rows), straight ds_reads
#pragma unroll
      for (int it = 0; it < 5; ++it) {
        const short8 za = *(const short8*)(&zg[(m + 16 * it) * 16]);
        acc[it][0] = __builtin_amdgcn_mfma_f32_16x16x32_bf16(za, wf0.v, acc[it][0], 0, 0, 0);
        acc[it][1] = __builtin_amdgcn_mfma_f32_16x16x32_bf16(za, wf1.v, acc[it][1], 0, 0, 0);
      }
    }
  }

  // write partials: rows 0..63 = M, row 64 = S; wave writes its own column half
  float* mp = Mpart + ((size_t)blockIdx.x * 8 + c) * (65 * 64);
#pragma unroll
  for (int it = 0; it < 5; ++it)
#pragma unroll
    for (int jt = 0; jt < 2; ++jt)
#pragma unroll
      for (int r = 0; r < 4; ++r) {
        const int rowi = it * 16 + g * 4 + r;
        if (rowi <= 64) mp[rowi * 64 + (2 * p + jt) * 16 + m] = acc[it][jt][r];
      }
}

// ---------------- reduce S (row 64 of partials) -> Sfin, mu, phi ----------------
__global__ void reduce_s_kernel(const float* __restrict__ Mpart,
                                const float* __restrict__ gsum,
                                float* __restrict__ Sfin,
                                float* __restrict__ phi_out, float* __restrict__ mu_out,
                                int nb, int N)
{
  __shared__ float sh[4][64];
  const int c = blockIdx.x;
  const int tid = threadIdx.x;
  const int q = tid >> 6, d = tid & 63;
  const int per = (nb + 3) >> 2;
  const int b0 = q * per, b1 = min(nb, b0 + per);
  float s = 0.f;
  for (int b = b0; b < b1; ++b)
    s += Mpart[((size_t)b * 8 + c) * 4160 + 4096 + d];
  sh[q][d] = s;
  __syncthreads();
  if (tid < 64) {
    const float t = sh[0][d] + sh[1][d] + sh[2][d] + sh[3][d];
    Sfin[c * 64 + d] = t;
    mu_out[c * 64 + d] = t / (gsum[c] + EPSV);
  }
  if (c == 0 && tid == 0) {
    float p[8], tot = 0.f;
    for (int j = 0; j < 8; ++j) { p[j] = gsum[j] / (float)N + EPSV / 8.f; tot += p[j]; }
    for (int j = 0; j < 8; ++j) phi_out[j] = p[j] / tot;
  }
}

// ---------------- reduce M (coalesced, one element per thread) -> sigma ----------
__global__ void reduce_m_kernel(const float* __restrict__ Mpart,
                                const float* __restrict__ Sfin,
                                const float* __restrict__ gsum,
                                float* __restrict__ sig_out, int nb)
{
  const int e = blockIdx.x * 128 + threadIdx.x;   // 0..32767 = (c, i, j); 256 blocks
  const int c = e >> 12;
  const int ij = e & 4095;
  const int i = ij >> 6, j = ij & 63;
  float s0 = 0.f, s1 = 0.f, s2 = 0.f, s3 = 0.f;
  int b = 0;
  for (; b + 3 < nb; b += 4) {
    s0 += Mpart[((size_t)(b + 0) * 8 + c) * 4160 + ij];
    s1 += Mpart[((size_t)(b + 1) * 8 + c) * 4160 + ij];
    s2 += Mpart[((size_t)(b + 2) * 8 + c) * 4160 + ij];
    s3 += Mpart[((size_t)(b + 3) * 8 + c) * 4160 + ij];
  }
  for (; b < nb; ++b)
    s0 += Mpart[((size_t)b * 8 + c) * 4160 + ij];
  const float msum = (s0 + s1) + (s2 + s3);
  const float gs = gsum[c];
  const float g1 = gs + EPSV;
  const float coef = (gs - 2.f * g1) / (g1 * g1 * g1);
  float v = msum / g1 + Sfin[c * 64 + i] * Sfin[c * 64 + j] * coef;
  if (i == j) v += EPSV;
  sig_out[e] = v;
}

extern "C" void kernel_launch(void* const* d_in, const int* in_sizes, int n_in,
                              void* d_out, int out_size, void* d_ws, size_t ws_size,
                              hipStream_t stream)
{
  const float* z   = (const float*)d_in[0];
  const float* lng = (const float*)d_in[1];
  const float* lnb = (const float*)d_in[2];
  const float* W1  = (const float*)d_in[3];
  const float* b1  = (const float*)d_in[4];
  const float* W2  = (const float*)d_in[5];
  const float* b2  = (const float*)d_in[6];
  const float* W3  = (const float*)d_in[7];
  const float* b3  = (const float*)d_in[8];
  const int N = in_sizes[0] / 64;

  float* out       = (float*)d_out;
  float* gamma_out = out;
  float* phi_out   = out + (size_t)N * 8;
  float* mu_out    = phi_out + 8;
  float* sig_out   = mu_out + 512;

  uint8_t* wsb = (uint8_t*)d_ws;
  float* gsum  = (float*)(wsb + WIMG);
  float* Sfin  = (float*)(wsb + WIMG + 32);
  float* Mpart = (float*)(wsb + WIMG + 32 + 2048);

  int nbB = 256;
  {
    const size_t need1 = (size_t)WIMG + 32 + 2048;
    const size_t avail = (ws_size > need1) ? ws_size - need1 : 0;
    size_t fit = avail / (4160ull * 8ull * 4ull);
    if (fit < 1) fit = 1;
    if ((size_t)nbB > fit) nbB = (int)fit;
  }
  int rpb = (N + nbB - 1) / nbB;
  rpb = (rpb + 127) & ~127;

  const int ntiles = (N + 15) / 16;

  prep_kernel<<<200, 256, 0, stream>>>(W1, W2, W3, wsb);
  mlp_kernel<<<256, 512, 0, stream>>>(z, lng, lnb, b1, b2, b3, wsb,
                                      gamma_out, gsum, N, ntiles);
  sigma_kernel<<<nbB, 1024, 0, stream>>>(z, gamma_out, Mpart, N, rpb);
  reduce_s_kernel<<<8, 256, 0, stream>>>(Mpart, gsum, Sfin, phi_out, mu_out, nbB, N);
  reduce_m_kernel<<<256, 128, 0, stream>>>(Mpart, Sfin, gsum, sig_out, nbB);
}

// Round 13
// 223.541 us; speedup vs baseline: 1.2545x; 1.0512x over previous
//
#include <hip/hip_runtime.h>
#include <hip/hip_bf16.h>
#include <stdint.h>

typedef __attribute__((ext_vector_type(8))) short short8;
typedef __attribute__((ext_vector_type(4))) float f32x4;
typedef __attribute__((ext_vector_type(4))) int i32x4;

constexpr float EPSV  = 1e-6f;
constexpr float LNEPS = 1e-5f;

// ---- workspace / LDS byte layout ----
constexpr int W1OFF = 0;          // 32768 B : W1^T bf16 [256 h][64 kslot], XOR-swizzled
constexpr int W2OFF = 32768;      // 65536 B : W2^T bf16 [128 h2][256 kslot], XOR-swizzled
constexpr int W3OFF = 98304;      //  4096 B : W3^T bf16 [16 r][128 kslot], XOR-swizzled
constexpr int WIMG  = 102400;     // total weight image
constexpr int XBOFF = 102400;     // LDS: Xb (8 chunks, padded stride)
constexpr int XCH   = 2080;       // Xb chunk stride bytes (128 n * 16B + 32 pad)
constexpr int LDSA  = WIMG + 8 * XCH;   // 119040 B
// NOTE (r1-r8 forensics): the r0 mlp body below is the ONLY variant the
// compiler allocates spill-free at 512 threads (VGPR 128, FETCH 34 MB,
// WRITE 23 MB). Every DATAFLOW deviation — pair-tiles (r2), reg-LN (r4/r5),
// fused stream (r6), W2-from-global (r8) — spilled 200-900 MB to scratch.
// r13 changes ONLY the f2bf arithmetic (hand-rolled 4-op RNE -> native
// __float2bfloat16, same RNE bits; compiler emits v_cvt_pk_bf16_f32 per
// T12/m240). Pointwise, fewer temporaries; dataflow untouched.
// NOTE (r10/r12): sigma barrier-frequency/occupancy theories falsified;
// r9 sigma structure (+128-row chunks, neutral) retained.

constexpr int ZCH   = 1312;       // sigma kernel: Ztb group stride (80 dims*16B + 32 pad)
constexpr int NG    = 16;         // 16 row-groups (128 rows/chunk)
constexpr int GTOFF = NG * ZCH;   // 20992
constexpr int LDSB  = GTOFF + 2048;     // + gamma [8c][128n] bf16 = 23040 B

__device__ __forceinline__ ushort f2bf(float f) {
  union { __hip_bfloat16 h; ushort u; } cv;
  cv.h = __float2bfloat16(f);              // RNE, HW cvt (pairs fuse to v_cvt_pk_bf16_f32)
  return cv.u;
}
__device__ __forceinline__ float bf2f(ushort h) {
  union { uint32_t u; float f; } v; v.u = ((uint32_t)h) << 16;
  return v.f;
}

// ---------------- prep: bake bf16 weight images + zero gsum (fused) ----------------
__global__ void prep_kernel(const float* __restrict__ W1, const float* __restrict__ W2,
                            const float* __restrict__ W3, uint8_t* __restrict__ wsb) {
  const int idx = blockIdx.x * 256 + threadIdx.x;   // 0..51199
  if (blockIdx.x == 0 && threadIdx.x < 8)
    ((float*)(wsb + WIMG))[threadIdx.x] = 0.f;      // gsum zero (disjoint region)
  ushort val; uint32_t a;
  if (idx < 16384) {                                // W1^T: slot p = 32s+8g+j -> k = p
    const int h = idx >> 6, p = idx & 63;
    a = ((uint32_t)(h * 128 + p * 2)) ^ ((uint32_t)(h & 7) << 4);
    val = f2bf(W1[p * 256 + h]);
  } else if (idx < 49152) {                         // W2^T
    const int i2 = idx - 16384;
    const int h2 = i2 >> 8, p = i2 & 255;
    const int s = p >> 5, g = (p >> 3) & 3, j = p & 7;
    const int k = 32 * s + 16 * (j >> 2) + 4 * g + (j & 3);
    a = (uint32_t)W2OFF + (((uint32_t)(h2 * 512 + p * 2)) ^ ((uint32_t)(h2 & 7) << 4));
    val = f2bf(W2[k * 128 + h2]);
  } else {                                          // W3^T padded to 16 rows
    const int i3 = idx - 49152;
    const int r = i3 >> 7, p = i3 & 127;
    const int s = p >> 5, g = (p >> 3) & 3, j = p & 7;
    const int k = 32 * s + 16 * (j >> 2) + 4 * g + (j & 3);
    a = (uint32_t)W3OFF + (((uint32_t)(r * 256 + p * 2)) ^ ((uint32_t)(r & 7) << 4));
    val = (r < 8) ? f2bf(W3[k * 8 + r]) : (ushort)0;
  }
  *(ushort*)(wsb + a) = val;
}

// ---------------- kernel A: persistent LN + 3-layer MLP (MFMA) + softmax ----
// Round-0 dataflow, verbatim (verified spill-free). Only f2bf impl changed.
__global__ __launch_bounds__(512, 1)
void mlp_kernel(const float* __restrict__ z,
                const float* __restrict__ lng, const float* __restrict__ lnb,
                const float* __restrict__ b1, const float* __restrict__ b2,
                const float* __restrict__ b3,
                const uint8_t* __restrict__ wimg,
                float* __restrict__ gamma_out, float* __restrict__ gsum,
                int N, int ntiles)
{
  __shared__ uint8_t lds[LDSA];
  const int tid = threadIdx.x;

  // stage weight image once (pre-swizzled; linear copy)
  {
    const i32x4* src = (const i32x4*)wimg;
    i32x4* dst = (i32x4*)lds;
    for (int i = tid; i < WIMG / 16; i += 512) dst[i] = src[i];
  }
  __syncthreads();

  const int lane = tid & 63;
  const int w = tid >> 6;            // wave id (owns its 16-row tiles)
  const int m = lane & 15;
  const int g = lane >> 4;           // also LN quarter
  const uint32_t swz = (uint32_t)((m & 7) << 4);

  f32x4 gacc = {0.f, 0.f, 0.f, 0.f};
  const int nwaves = gridDim.x * 8;

  for (int t = blockIdx.x * 8 + w; t < ntiles; t += nwaves) {
    const int64_t n0 = (int64_t)t * 16;

    // ---- in-wave LayerNorm: lane (r=m, q=g) handles row n0+m, dims 16g..16g+15 ----
    {
      int64_t row = n0 + m;
      if (row >= N) row = N - 1;
      const f32x4* zr = (const f32x4*)(z + row * 64 + g * 16);
      f32x4 zv[4];
      float s = 0.f, s2 = 0.f;
#pragma unroll
      for (int k = 0; k < 4; ++k) {
        zv[k] = zr[k];
#pragma unroll
        for (int e = 0; e < 4; ++e) { s += zv[k][e]; s2 = fmaf(zv[k][e], zv[k][e], s2); }
      }
      s  += __shfl_xor(s, 16);  s  += __shfl_xor(s, 32);
      s2 += __shfl_xor(s2, 16); s2 += __shfl_xor(s2, 32);
      const float mean = s * (1.f / 64.f);
      const float rstd = rsqrtf(s2 * (1.f / 64.f) - mean * mean + LNEPS);
#pragma unroll
      for (int h = 0; h < 2; ++h) {
        union { short8 v; ushort u[8]; } pk;
#pragma unroll
        for (int i = 0; i < 8; ++i) {
          const int li = h * 8 + i;            // 0..15 within quarter
          const int d = g * 16 + li;
          const float x = fmaf((zv[li >> 2][li & 3] - mean) * rstd, lng[d], lnb[d]);
          pk.u[i] = f2bf(x);
        }
        *(short8*)(&lds[XBOFF + (2 * g + h) * XCH + (16 * w + m) * 16]) = pk.v;
      }
    }
    // no barrier: wave reads back only its own rows

    // ---- GEMM1: H1^T = W1^T @ X^T (16 h-tiles, k=64 -> 2 steps) ----
    f32x4 acc1[16];
#pragma unroll
    for (int ht = 0; ht < 16; ++ht)
      acc1[ht] = *(const f32x4*)(b1 + ht * 16 + g * 4);
#pragma unroll
    for (int s = 0; s < 2; ++s) {
      const short8 bfrag = *(const short8*)(&lds[XBOFF + (4 * s + g) * XCH + (16 * w + m) * 16]);
      const uint32_t koff = ((uint32_t)(64 * s + 16 * g)) ^ swz;
#pragma unroll
      for (int ht = 0; ht < 16; ++ht) {
        const short8 afrag = *(const short8*)(&lds[(uint32_t)((m + 16 * ht) * 128) + koff]);
        acc1[ht] = __builtin_amdgcn_mfma_f32_16x16x32_bf16(afrag, bfrag, acc1[ht], 0, 0, 0);
      }
    }

    // relu + pack -> B-frags for GEMM2
    short8 h1f[8];
#pragma unroll
    for (int s = 0; s < 8; ++s) {
      union { short8 v; ushort u[8]; } pk;
#pragma unroll
      for (int e = 0; e < 4; ++e) pk.u[e]     = f2bf(fmaxf(acc1[2 * s][e],     0.f));
#pragma unroll
      for (int e = 0; e < 4; ++e) pk.u[4 + e] = f2bf(fmaxf(acc1[2 * s + 1][e], 0.f));
      h1f[s] = pk.v;
    }

    // ---- GEMM2: H2^T = W2^T @ H1^T (8 h2-tiles, k=256 -> 8 steps) ----
    f32x4 acc2[8];
#pragma unroll
    for (int at = 0; at < 8; ++at)
      acc2[at] = *(const f32x4*)(b2 + at * 16 + g * 4);
#pragma unroll
    for (int s = 0; s < 8; ++s) {
      const uint32_t koff = ((uint32_t)(64 * s + 16 * g)) ^ swz;
#pragma unroll
      for (int at = 0; at < 8; ++at) {
        const short8 afrag = *(const short8*)(&lds[(uint32_t)W2OFF + (uint32_t)((m + 16 * at) * 512) + koff]);
        acc2[at] = __builtin_amdgcn_mfma_f32_16x16x32_bf16(afrag, h1f[s], acc2[at], 0, 0, 0);
      }
    }

    short8 h2f[4];
#pragma unroll
    for (int s = 0; s < 4; ++s) {
      union { short8 v; ushort u[8]; } pk;
#pragma unroll
      for (int e = 0; e < 4; ++e) pk.u[e]     = f2bf(fmaxf(acc2[2 * s][e],     0.f));
#pragma unroll
      for (int e = 0; e < 4; ++e) pk.u[4 + e] = f2bf(fmaxf(acc2[2 * s + 1][e], 0.f));
      h2f[s] = pk.v;
    }

    // ---- GEMM3: logits^T = W3^T @ H2^T (1 tile, k=128 -> 4 steps) ----
    f32x4 acc3;
    if (g < 2) acc3 = *(const f32x4*)(b3 + 4 * g);
    else       acc3 = (f32x4){0.f, 0.f, 0.f, 0.f};
#pragma unroll
    for (int s = 0; s < 4; ++s) {
      const uint32_t koff = ((uint32_t)(64 * s + 16 * g)) ^ swz;
      const short8 afrag = *(const short8*)(&lds[(uint32_t)W3OFF + (uint32_t)(m * 256) + koff]);
      acc3 = __builtin_amdgcn_mfma_f32_16x16x32_bf16(afrag, h2f[s], acc3, 0, 0, 0);
    }

    // ---- softmax over K=8 (rows split across lane-groups 0,1; col = batch row) ----
    float mx = fmaxf(fmaxf(acc3[0], acc3[1]), fmaxf(acc3[2], acc3[3]));
    mx = fmaxf(mx, __shfl_xor(mx, 16));
    const float e0 = __expf(acc3[0] - mx), e1 = __expf(acc3[1] - mx);
    const float e2 = __expf(acc3[2] - mx), e3 = __expf(acc3[3] - mx);
    float se = e0 + e1 + e2 + e3;
    se += __shfl_xor(se, 16);
    const float inv = 1.f / se;

    const int64_t rowg = n0 + m;
    const bool valid = (g < 2) && (rowg < N);
    const f32x4 gv = { e0 * inv, e1 * inv, e2 * inv, e3 * inv };
    if (valid) {
      *(f32x4*)(gamma_out + rowg * 8 + 4 * g) = gv;
      gacc[0] += gv[0]; gacc[1] += gv[1]; gacc[2] += gv[2]; gacc[3] += gv[3];
    }
  }

  // one atomic batch per wave
#pragma unroll
  for (int i = 0; i < 4; ++i) {
    float v = gacc[i];
    v += __shfl_xor(v, 1); v += __shfl_xor(v, 2);
    v += __shfl_xor(v, 4); v += __shfl_xor(v, 8);
    if (m == 0 && g < 2) atomicAdd(&gsum[4 * g + i], v);
  }
}

// ---------------- kernel B: M_c = Zhat^T (gamma_c .* Z) via MFMA (Zhat dim64 = 1) ----
// r9 structure with 128-row chunks (r12, verified neutral-best): wave (c, p)
// owns columns 32p..32p+31 of component c; gamma on the B side (2 frags/kg);
// 2 barriers/chunk, register prefetch of next chunk before the MFMA phase.
__global__ __launch_bounds__(1024)
void sigma_kernel(const float* __restrict__ z, const float* __restrict__ gamma,
                  float* __restrict__ Mpart, int N, int rpb)
{
  __shared__ uint8_t lds[LDSB];
  const int tid = threadIdx.x;
  const int lane = tid & 63;
  const int w = tid >> 6;           // 0..15
  const int c = w & 7;              // component
  const int p = w >> 3;             // column half
  const int m = lane & 15;
  const int g = lane >> 4;

  // constant pad dims 64..79 for all 16 groups (dim 64 = 1.0 -> S row; 65..79 = 0)
  {
    const int dd = 64 + ((tid >> 3) & 15), jj = tid & 7;
    const ushort pv = (dd == 64) ? (ushort)0x3F80 : (ushort)0;
    *(ushort*)(&lds[(tid >> 7) * ZCH + dd * 16 + jj * 2]) = pv;
    *(ushort*)(&lds[((tid >> 7) + 8) * ZCH + dd * 16 + jj * 2]) = pv;
  }

  f32x4 acc[5][2];
#pragma unroll
  for (int it = 0; it < 5; ++it)
#pragma unroll
    for (int jt = 0; jt < 2; ++jt) acc[it][jt] = (f32x4){0.f, 0.f, 0.f, 0.f};

  const int64_t row0 = (int64_t)blockIdx.x * rpb;
  const int n16 = tid >> 4, d0 = (tid & 15) * 4;   // staging: row-in-half-chunk, dim base
  const int gc = n16 >> 3, jn = n16 & 7;

  f32x4 zpre0, zpre1; float gpre = 0.f;
  {   // prologue prefetch chunk 0 (rows n16 and n16+64)
    int64_t r0z = row0 + n16;      if (r0z >= N) r0z = N - 1;
    int64_t r1z = row0 + 64 + n16; if (r1z >= N) r1z = N - 1;
    zpre0 = *(const f32x4*)(z + r0z * 64 + d0);
    zpre1 = *(const f32x4*)(z + r1z * 64 + d0);
    const int64_t rg = row0 + (tid >> 3);
    gpre = (rg < N) ? gamma[rg * 8 + (tid & 7)] : 0.f;
  }

  for (int rr = 0; rr < rpb; rr += 128) {
    __syncthreads();
    {   // write staged chunk -> LDS (transposed-blocked [group][dim][8n] bf16)
#pragma unroll
      for (int i = 0; i < 4; ++i) {
        *(ushort*)(&lds[gc * ZCH + (d0 + i) * 16 + jn * 2])       = f2bf(zpre0[i]);
        *(ushort*)(&lds[(gc + 8) * ZCH + (d0 + i) * 16 + jn * 2]) = f2bf(zpre1[i]);
      }
      *(ushort*)(&lds[GTOFF + (tid & 7) * 256 + (tid >> 3) * 2]) = f2bf(gpre);
    }
    __syncthreads();

    // issue next chunk's loads (latency hides under the MFMA phase below)
    if (rr + 128 < rpb) {
      int64_t r0z = row0 + rr + 128 + n16;      if (r0z >= N) r0z = N - 1;
      int64_t r1z = row0 + rr + 128 + 64 + n16; if (r1z >= N) r1z = N - 1;
      zpre0 = *(const f32x4*)(z + r0z * 64 + d0);
      zpre1 = *(const f32x4*)(z + r1z * 64 + d0);
      const int64_t rg = row0 + rr + 128 + (tid >> 3);
      gpre = (rg < N) ? gamma[rg * 8 + (tid & 7)] : 0.f;
    }

#pragma unroll
    for (int kg = 0; kg < 4; ++kg) {
      union { short8 v; ushort u[8]; } gu;
      gu.v = *(const short8*)(&lds[GTOFF + c * 256 + kg * 64 + g * 16]);
      float gf[8];
#pragma unroll
      for (int j = 0; j < 8; ++j) gf[j] = bf2f(gu.u[j]);

      const uint8_t* zg = &lds[(4 * kg + g) * ZCH];
      // gamma-weight the 2 B-frags (columns 32p..32p+31)
      union { short8 v; ushort u[8]; } zb0, zb1, wf0, wf1;
      zb0.v = *(const short8*)(&zg[(m + 16 * (2 * p + 0)) * 16]);
      zb1.v = *(const short8*)(&zg[(m + 16 * (2 * p + 1)) * 16]);
#pragma unroll
      for (int j = 0; j < 8; ++j) {
        wf0.u[j] = f2bf(gf[j] * bf2f(zb0.u[j]));
        wf1.u[j] = f2bf(gf[j] * bf2f(zb1.u[j]));
      }
      // A side: raw Zhat fragments (incl. pad rows), straight ds_reads
#pragma unroll
      for (int it = 0; it < 5; ++it) {
        const short8 za = *(const short8*)(&zg[(m + 16 * it) * 16]);
        acc[it][0] = __builtin_amdgcn_mfma_f32_16x16x32_bf16(za, wf0.v, acc[it][0], 0, 0, 0);
        acc[it][1] = __builtin_amdgcn_mfma_f32_16x16x32_bf16(za, wf1.v, acc[it][1], 0, 0, 0);
      }
    }
  }

  // write partials: rows 0..63 = M, row 64 = S; wave writes its own column half
  float* mp = Mpart + ((size_t)blockIdx.x * 8 + c) * (65 * 64);
#pragma unroll
  for (int it = 0; it < 5; ++it)
#pragma unroll
    for (int jt = 0; jt < 2; ++jt)
#pragma unroll
      for (int r = 0; r < 4; ++r) {
        const int rowi = it * 16 + g * 4 + r;
        if (rowi <= 64) mp[rowi * 64 + (2 * p + jt) * 16 + m] = acc[it][jt][r];
      }
}

// ---------------- reduce S (row 64 of partials) -> Sfin, mu, phi ----------------
__global__ void reduce_s_kernel(const float* __restrict__ Mpart,
                                const float* __restrict__ gsum,
                                float* __restrict__ Sfin,
                                float* __restrict__ phi_out, float* __restrict__ mu_out,
                                int nb, int N)
{
  __shared__ float sh[4][64];
  const int c = blockIdx.x;
  const int tid = threadIdx.x;
  const int q = tid >> 6, d = tid & 63;
  const int per = (nb + 3) >> 2;
  const int b0 = q * per, b1 = min(nb, b0 + per);
  float s = 0.f;
  for (int b = b0; b < b1; ++b)
    s += Mpart[((size_t)b * 8 + c) * 4160 + 4096 + d];
  sh[q][d] = s;
  __syncthreads();
  if (tid < 64) {
    const float t = sh[0][d] + sh[1][d] + sh[2][d] + sh[3][d];
    Sfin[c * 64 + d] = t;
    mu_out[c * 64 + d] = t / (gsum[c] + EPSV);
  }
  if (c == 0 && tid == 0) {
    float p[8], tot = 0.f;
    for (int j = 0; j < 8; ++j) { p[j] = gsum[j] / (float)N + EPSV / 8.f; tot += p[j]; }
    for (int j = 0; j < 8; ++j) phi_out[j] = p[j] / tot;
  }
}

// ---------------- reduce M (coalesced, one element per thread) -> sigma ----------
__global__ void reduce_m_kernel(const float* __restrict__ Mpart,
                                const float* __restrict__ Sfin,
                                const float* __restrict__ gsum,
                                float* __restrict__ sig_out, int nb)
{
  const int e = blockIdx.x * 128 + threadIdx.x;   // 0..32767 = (c, i, j); 256 blocks
  const int c = e >> 12;
  const int ij = e & 4095;
  const int i = ij >> 6, j = ij & 63;
  float s0 = 0.f, s1 = 0.f, s2 = 0.f, s3 = 0.f;
  int b = 0;
  for (; b + 3 < nb; b += 4) {
    s0 += Mpart[((size_t)(b + 0) * 8 + c) * 4160 + ij];
    s1 += Mpart[((size_t)(b + 1) * 8 + c) * 4160 + ij];
    s2 += Mpart[((size_t)(b + 2) * 8 + c) * 4160 + ij];
    s3 += Mpart[((size_t)(b + 3) * 8 + c) * 4160 + ij];
  }
  for (; b < nb; ++b)
    s0 += Mpart[((size_t)b * 8 + c) * 4160 + ij];
  const float msum = (s0 + s1) + (s2 + s3);
  const float gs = gsum[c];
  const float g1 = gs + EPSV;
  const float coef = (gs - 2.f * g1) / (g1 * g1 * g1);
  float v = msum / g1 + Sfin[c * 64 + i] * Sfin[c * 64 + j] * coef;
  if (i == j) v += EPSV;
  sig_out[e] = v;
}

extern "C" void kernel_launch(void* const* d_in, const int* in_sizes, int n_in,
                              void* d_out, int out_size, void* d_ws, size_t ws_size,
                              hipStream_t stream)
{
  const float* z   = (const float*)d_in[0];
  const float* lng = (const float*)d_in[1];
  const float* lnb = (const float*)d_in[2];
  const float* W1  = (const float*)d_in[3];
  const float* b1  = (const float*)d_in[4];
  const float* W2  = (const float*)d_in[5];
  const float* b2  = (const float*)d_in[6];
  const float* W3  = (const float*)d_in[7];
  const float* b3  = (const float*)d_in[8];
  const int N = in_sizes[0] / 64;

  float* out       = (float*)d_out;
  float* gamma_out = out;
  float* phi_out   = out + (size_t)N * 8;
  float* mu_out    = phi_out + 8;
  float* sig_out   = mu_out + 512;

  uint8_t* wsb = (uint8_t*)d_ws;
  float* gsum  = (float*)(wsb + WIMG);
  float* Sfin  = (float*)(wsb + WIMG + 32);
  float* Mpart = (float*)(wsb + WIMG + 32 + 2048);

  int nbB = 256;
  {
    const size_t need1 = (size_t)WIMG + 32 + 2048;
    const size_t avail = (ws_size > need1) ? ws_size - need1 : 0;
    size_t fit = avail / (4160ull * 8ull * 4ull);
    if (fit < 1) fit = 1;
    if ((size_t)nbB > fit) nbB = (int)fit;
  }
  int rpb = (N + nbB - 1) / nbB;
  rpb = (rpb + 127) & ~127;

  const int ntiles = (N + 15) / 16;

  prep_kernel<<<200, 256, 0, stream>>>(W1, W2, W3, wsb);
  mlp_kernel<<<256, 512, 0, stream>>>(z, lng, lnb, b1, b2, b3, wsb,
                                      gamma_out, gsum, N, ntiles);
  sigma_kernel<<<nbB, 1024, 0, stream>>>(z, gamma_out, Mpart, N, rpb);
  reduce_s_kernel<<<8, 256, 0, stream>>>(Mpart, gsum, Sfin, phi_out, mu_out, nbB, N);
  reduce_m_kernel<<<256, 128, 0, stream>>>(Mpart, Sfin, gsum, sig_out, nbB);
}